// Round 21
// baseline (53.580 us; speedup 1.0000x reference)
//
#include <hip/hip_runtime.h>

#define NN 50000
#define NE 100000
#define NREL 64
#define D 64
#define RCAP 1280      // per-relation bucket capacity (expected ~676)
#define SCAP 8192      // self-only bucket capacity (expected ~6766)
#define CSTR 16        // cursor stride in ints (64 B per counter)
#define BR   8         // blocks per relation
#define SBLK 64        // self-only blocks
#define FILL_BLOCKS 128
#define FILL_ITERS  2

typedef unsigned long long u64;
using f16x8 = __attribute__((ext_vector_type(8))) _Float16;
using f32x4 = __attribute__((ext_vector_type(4))) float;

// ws layout (bytes): packed [0,400000) | cursor @512K | rbucket @520K (327.7KB) |
// sbucket @896K (32KB) | h2 (f16) @1M (6.4MB)
#define WS_CURSOR  (512 * 1024)
#define WS_RBUCKET (520 * 1024)
#define WS_SBUCKET (896 * 1024)
#define WS_H2      (1024 * 1024)

struct H4 { _Float16 v[4]; };   // 8-byte pack

// init packed/cursor + convert h (f32) -> h2 (f16)
__global__ __launch_bounds__(256) void k_pre(
    const float* __restrict__ h, u64* __restrict__ packed,
    int* __restrict__ cursor, _Float16* __restrict__ h2)
{
    const int t = blockIdx.x * 256 + threadIdx.x;
    const int nthr = gridDim.x * 256;
    for (int i = t; i < NN; i += nthr) packed[i] = 0ull;
    if (t < 65) cursor[t * CSTR] = 0;

    const float4* __restrict__ hf4 = reinterpret_cast<const float4*>(h);
    H4* __restrict__ o4 = reinterpret_cast<H4*>(h2);
    for (int m = t; m < NN * (D / 4); m += nthr) {
        const float4 p = hf4[m];
        H4 o;
        o.v[0] = (_Float16)p.x; o.v[1] = (_Float16)p.y;
        o.v[2] = (_Float16)p.z; o.v[3] = (_Float16)p.w;
        o4[m] = o;
    }
}

// one 64-bit atomicMax per edge: key = (e+1)<<22 | rel<<16 | src
__global__ void k_scatter(const int* __restrict__ edges, u64* __restrict__ packed) {
    int e = blockIdx.x * blockDim.x + threadIdx.x;
    if (e < NE) {
        int s = edges[e * 3 + 0];
        int r = edges[e * 3 + 1];
        int d = edges[e * 3 + 2];
        u64 key = ((u64)(e + 1) << 22) | ((u64)r << 16) | (u64)s;
        atomicMax(&packed[d], key);
    }
}

// block-aggregated bucket fill: LDS histogram -> 1 global atomic per (block, rel)
__global__ __launch_bounds__(256) void k_fill(
    const u64* __restrict__ packed, int* __restrict__ cursor,
    unsigned* __restrict__ rbucket, unsigned* __restrict__ sbucket)
{
    __shared__ int hcnt[65];
    __shared__ int hbase[65];
    const int t = threadIdx.x;
    if (t < 65) hcnt[t] = 0;
    __syncthreads();

    int      myr[FILL_ITERS];
    int      myslot[FILL_ITERS];
    unsigned myent[FILL_ITERS];

    #pragma unroll
    for (int it = 0; it < FILL_ITERS; ++it) {
        const int v = (blockIdx.x * FILL_ITERS + it) * 256 + t;
        myr[it] = -1;
        if (v < NN) {
            u64 key = packed[v];
            if (key) {
                myr[it]   = (int)((key >> 16) & 63);
                myent[it] = ((unsigned)v << 16) | (unsigned)(key & 0xFFFF);
            } else {
                myr[it]   = 64;
                myent[it] = (unsigned)v;
            }
            myslot[it] = atomicAdd(&hcnt[myr[it]], 1);
        }
    }
    __syncthreads();
    if (t < 65 && hcnt[t] > 0)
        hbase[t] = atomicAdd(&cursor[t * CSTR], hcnt[t]);
    __syncthreads();

    #pragma unroll
    for (int it = 0; it < FILL_ITERS; ++it) {
        const int r = myr[it];
        if (r >= 0) {
            const int p = hbase[r] + myslot[it];
            if (r < 64) { if (p < RCAP) rbucket[r * RCAP + p] = myent[it]; }
            else        { if (p < SCAP) sbucket[p] = myent[it]; }
        }
    }
}

// MFMA compute (r15-verified): per 16-node tile, out[16x64] = Hs @ W[r] + Hv @ WS.
__global__ __launch_bounds__(256) void k_compute(
    const _Float16* __restrict__ h2, const float* __restrict__ weight,
    const float* __restrict__ wself, const unsigned* __restrict__ rbucket,
    const unsigned* __restrict__ sbucket, const int* __restrict__ cursor,
    float* __restrict__ out)
{
    __shared__ _Float16 lds_w[D * D];    // W[r]    8 KiB (f16)
    __shared__ _Float16 lds_ws[D * D];   // W_self  8 KiB (f16)

    const int lane = threadIdx.x & 63;
    const int wv   = threadIdx.x >> 6;
    const bool isRel = blockIdx.x < NREL * BR;

    int r = 64, wslot, wstride, cnt;
    const unsigned* __restrict__ seg;
    if (isRel) {
        r = blockIdx.x / BR;
        wslot = (blockIdx.x % BR) * 4 + wv;
        wstride = BR * 4;
        seg = rbucket + r * RCAP;
        cnt = min(cursor[r * CSTR], RCAP);
    } else {
        wslot = (blockIdx.x - NREL * BR) * 4 + wv;
        wstride = SBLK * 4;
        seg = sbucket;
        cnt = min(cursor[64 * CSTR], SCAP);
    }
    if (cnt == 0) return;   // block-uniform

    // ---- stage weights to LDS as f16 ----
    if (isRel) {
        const float4* __restrict__ W4 = reinterpret_cast<const float4*>(weight + (size_t)r * D * D);
        for (int i = threadIdx.x; i < D * D / 4; i += 256) {
            const float4 w = W4[i];
            H4 o; o.v[0]=(_Float16)w.x; o.v[1]=(_Float16)w.y; o.v[2]=(_Float16)w.z; o.v[3]=(_Float16)w.w;
            *reinterpret_cast<H4*>(&lds_w[i * 4]) = o;
        }
    }
    {
        const float4* __restrict__ WS4 = reinterpret_cast<const float4*>(wself);
        for (int i = threadIdx.x; i < D * D / 4; i += 256) {
            const float4 w = WS4[i];
            H4 o; o.v[0]=(_Float16)w.x; o.v[1]=(_Float16)w.y; o.v[2]=(_Float16)w.z; o.v[3]=(_Float16)w.w;
            *reinterpret_cast<H4*>(&lds_ws[i * 4]) = o;
        }
    }
    __syncthreads();

    // ---- build B-frags once per wave (loop-invariant) ----
    const int kbase = (lane >> 4) * 8;
    const int ncol  = lane & 15;

    f16x8 bws[4][2];                       // [n-tile][k-step]
    #pragma unroll
    for (int nt = 0; nt < 4; ++nt)
        #pragma unroll
        for (int ks = 0; ks < 2; ++ks) {
            f16x8 f;
            #pragma unroll
            for (int j = 0; j < 8; ++j)
                f[j] = lds_ws[(ks * 32 + kbase + j) * D + nt * 16 + ncol];
            bws[nt][ks] = f;
        }

    f16x8 bw[4][2];
    if (isRel) {
        #pragma unroll
        for (int nt = 0; nt < 4; ++nt)
            #pragma unroll
            for (int ks = 0; ks < 2; ++ks) {
                f16x8 f;
                #pragma unroll
                for (int j = 0; j < 8; ++j)
                    f[j] = lds_w[(ks * 32 + kbase + j) * D + nt * 16 + ncol];
                bw[nt][ks] = f;
            }
    }

    // ---- tile loop ----
    for (int t = wslot; t * 16 < cnt; t += wstride) {
        const int myidx = min(t * 16 + ncol, cnt - 1);   // this lane's tile row = ncol
        const unsigned ent = seg[myidx];
        const int v = isRel ? (int)(ent >> 16) : (int)ent;
        const int s = (int)(ent & 0xFFFF);

        f32x4 c[4];
        #pragma unroll
        for (int nt = 0; nt < 4; ++nt) c[nt] = (f32x4){0.f, 0.f, 0.f, 0.f};

        // self part: A = h2[v]
        {
            const f16x8 a0 = *reinterpret_cast<const f16x8*>(h2 + (size_t)v * D + kbase);
            const f16x8 a1 = *reinterpret_cast<const f16x8*>(h2 + (size_t)v * D + 32 + kbase);
            #pragma unroll
            for (int nt = 0; nt < 4; ++nt) {
                c[nt] = __builtin_amdgcn_mfma_f32_16x16x32_f16(a0, bws[nt][0], c[nt], 0, 0, 0);
                c[nt] = __builtin_amdgcn_mfma_f32_16x16x32_f16(a1, bws[nt][1], c[nt], 0, 0, 0);
            }
        }
        // rel part: A = h2[s]
        if (isRel) {
            const f16x8 a0 = *reinterpret_cast<const f16x8*>(h2 + (size_t)s * D + kbase);
            const f16x8 a1 = *reinterpret_cast<const f16x8*>(h2 + (size_t)s * D + 32 + kbase);
            #pragma unroll
            for (int nt = 0; nt < 4; ++nt) {
                c[nt] = __builtin_amdgcn_mfma_f32_16x16x32_f16(a0, bw[nt][0], c[nt], 0, 0, 0);
                c[nt] = __builtin_amdgcn_mfma_f32_16x16x32_f16(a1, bw[nt][1], c[nt], 0, 0, 0);
            }
        }

        // store: reg q holds row m=(lane>>4)*4+q, col = ncol
        int vrow[4];
        #pragma unroll
        for (int q = 0; q < 4; ++q)
            vrow[q] = __shfl(v, (lane >> 4) * 4 + q, 64);

        #pragma unroll
        for (int nt = 0; nt < 4; ++nt)
            #pragma unroll
            for (int q = 0; q < 4; ++q)
                out[(size_t)vrow[q] * D + nt * 16 + ncol] = c[nt][q];
    }
}

extern "C" void kernel_launch(void* const* d_in, const int* in_sizes, int n_in,
                              void* d_out, int out_size, void* d_ws, size_t ws_size,
                              hipStream_t stream) {
    const float* h      = (const float*)d_in[0];
    const int*   edges  = (const int*)d_in[1];
    const float* weight = (const float*)d_in[2];
    const float* wself  = (const float*)d_in[3];
    float* out = (float*)d_out;

    char* ws = (char*)d_ws;
    u64*      packed  = (u64*)ws;
    int*      cursor  = (int*)(ws + WS_CURSOR);
    unsigned* rbucket = (unsigned*)(ws + WS_RBUCKET);
    unsigned* sbucket = (unsigned*)(ws + WS_SBUCKET);
    _Float16* h2      = (_Float16*)(ws + WS_H2);

    k_pre<<<512, 256, 0, stream>>>(h, packed, cursor, h2);
    k_scatter<<<(NE + 255) / 256, 256, 0, stream>>>(edges, packed);
    k_fill<<<FILL_BLOCKS, 256, 0, stream>>>(packed, cursor, rbucket, sbucket);
    // MEASUREMENT: k_compute launched 3x (idempotent - identical writes).
    // total = base + 2*(c+gap) isolates k_compute's true cost.
    k_compute<<<NREL * BR + SBLK, 256, 0, stream>>>(h2, weight, wself, rbucket, sbucket, cursor, out);
    k_compute<<<NREL * BR + SBLK, 256, 0, stream>>>(h2, weight, wself, rbucket, sbucket, cursor, out);
    k_compute<<<NREL * BR + SBLK, 256, 0, stream>>>(h2, weight, wself, rbucket, sbucket, cursor, out);
}

// Round 23
// 47.034 us; speedup vs baseline: 1.1392x; 1.1392x over previous
//
#include <hip/hip_runtime.h>

#define NN 50000
#define NE 100000
#define NREL 64
#define D 64
#define RCAP 1280      // per-relation bucket capacity (expected ~676)
#define CSTR 16        // cursor stride in ints (64 B per counter)
#define BR   8         // rel blocks per relation
#define SC_BLK ((NE + 255) / 256)          // 391 scatter blocks
#define DN_BLK 782                         // dense-self blocks: 782*4 waves = 3128 tiles >= 3125

typedef unsigned long long u64;
using f16x8 = __attribute__((ext_vector_type(8))) _Float16;
using f32x4 = __attribute__((ext_vector_type(4))) float;

// ws layout (bytes): packed @0 (400KB) | cursor @400K (4KB) | rbucket @408K (327.7KB)
#define WS_CURSOR  (400 * 1024)
#define WS_RBUCKET (408 * 1024)

struct H4 { _Float16 v[4]; };

__global__ __launch_bounds__(256) void k_zero(u64* __restrict__ packed, int* __restrict__ cursor) {
    const int t = blockIdx.x * 256 + threadIdx.x;
    const int nthr = gridDim.x * 256;
    for (int i = t; i < NN; i += nthr) packed[i] = 0ull;
    if (t < 64) cursor[t * CSTR] = 0;
}

__device__ __forceinline__ f16x8 cvt_frag(const float* __restrict__ p) {
    const float4 p0 = *reinterpret_cast<const float4*>(p);
    const float4 p1 = *reinterpret_cast<const float4*>(p + 4);
    f16x8 a;
    a[0] = (_Float16)p0.x; a[1] = (_Float16)p0.y; a[2] = (_Float16)p0.z; a[3] = (_Float16)p0.w;
    a[4] = (_Float16)p1.x; a[5] = (_Float16)p1.y; a[6] = (_Float16)p1.z; a[7] = (_Float16)p1.w;
    return a;
}

// fused: [0,SC_BLK) edge scatter (atomicMax winner) | [SC_BLK,+DN_BLK) dense
// self pass out[v] = h[v] @ WS for ALL nodes (rel nodes overwritten by k_rel).
__global__ __launch_bounds__(256) void k_scatdense(
    const int* __restrict__ edges, const float* __restrict__ h,
    const float* __restrict__ wself, u64* __restrict__ packed,
    float* __restrict__ out)
{
    __shared__ _Float16 lds_ws[D * D];   // 8 KiB f16

    if (blockIdx.x < SC_BLK) {
        const int e = blockIdx.x * 256 + threadIdx.x;
        if (e < NE) {
            const int s = edges[e * 3 + 0];
            const int r = edges[e * 3 + 1];
            const int d = edges[e * 3 + 2];
            const u64 key = ((u64)(e + 1) << 22) | ((u64)r << 16) | (u64)s;
            atomicMax(&packed[d], key);
        }
        return;
    }

    // ---- dense self: stage WS -> LDS f16 ----
    {
        const float4* __restrict__ WS4 = reinterpret_cast<const float4*>(wself);
        for (int i = threadIdx.x; i < D * D / 4; i += 256) {
            const float4 w = WS4[i];
            H4 o; o.v[0]=(_Float16)w.x; o.v[1]=(_Float16)w.y; o.v[2]=(_Float16)w.z; o.v[3]=(_Float16)w.w;
            *reinterpret_cast<H4*>(&lds_ws[i * 4]) = o;
        }
    }
    __syncthreads();

    const int lane = threadIdx.x & 63;
    const int wv   = threadIdx.x >> 6;
    const int kbase = (lane >> 4) * 8;
    const int ncol  = lane & 15;

    f16x8 bws[4][2];
    #pragma unroll
    for (int nt = 0; nt < 4; ++nt)
        #pragma unroll
        for (int ks = 0; ks < 2; ++ks) {
            f16x8 f;
            #pragma unroll
            for (int j = 0; j < 8; ++j)
                f[j] = lds_ws[(ks * 32 + kbase + j) * D + nt * 16 + ncol];
            bws[nt][ks] = f;
        }

    const int tt = (blockIdx.x - SC_BLK) * 4 + wv;      // tile id (16 rows each)
    if (tt * 16 >= NN) return;
    const int v = min(tt * 16 + ncol, NN - 1);          // clamped tail: dup identical stores

    const float* __restrict__ hv = h + (size_t)v * D;
    const f16x8 a0 = cvt_frag(hv + kbase);
    const f16x8 a1 = cvt_frag(hv + 32 + kbase);

    f32x4 c[4];
    #pragma unroll
    for (int nt = 0; nt < 4; ++nt) c[nt] = (f32x4){0.f, 0.f, 0.f, 0.f};
    #pragma unroll
    for (int nt = 0; nt < 4; ++nt) {
        c[nt] = __builtin_amdgcn_mfma_f32_16x16x32_f16(a0, bws[nt][0], c[nt], 0, 0, 0);
        c[nt] = __builtin_amdgcn_mfma_f32_16x16x32_f16(a1, bws[nt][1], c[nt], 0, 0, 0);
    }

    int vrow[4];
    #pragma unroll
    for (int q = 0; q < 4; ++q)
        vrow[q] = __shfl(v, (lane >> 4) * 4 + q, 64);
    #pragma unroll
    for (int nt = 0; nt < 4; ++nt)
        #pragma unroll
        for (int q = 0; q < 4; ++q)
            out[(size_t)vrow[q] * D + nt * 16 + ncol] = c[nt][q];
}

// edge-driven bucket fill: edge e owns dst iff its key won the atomicMax.
__global__ __launch_bounds__(256) void k_fille(
    const int* __restrict__ edges, const u64* __restrict__ packed,
    int* __restrict__ cursor, unsigned* __restrict__ rbucket)
{
    const int e = blockIdx.x * 256 + threadIdx.x;
    if (e < NE) {
        const int d = edges[e * 3 + 2];
        const u64 key = packed[d];
        if ((int)(key >> 22) == e + 1) {            // unique winner
            const int r = (int)((key >> 16) & 63);
            const int p = atomicAdd(&cursor[r * CSTR], 1);
            if (p < RCAP)
                rbucket[r * RCAP + p] = ((unsigned)d << 16) | (unsigned)(key & 0xFFFF);
        }
    }
}

// rel compute (r15-verified tile machinery): out[v] = Hs @ W[r] + Hv @ WS
// (OVERWRITES the dense self value; single store, no RMW).
__global__ __launch_bounds__(256) void k_rel(
    const float* __restrict__ h, const float* __restrict__ weight,
    const float* __restrict__ wself, const unsigned* __restrict__ rbucket,
    const int* __restrict__ cursor, float* __restrict__ out)
{
    __shared__ _Float16 lds_w[D * D];    // W[r]    8 KiB f16
    __shared__ _Float16 lds_ws[D * D];   // W_self  8 KiB f16

    const int lane = threadIdx.x & 63;
    const int wv   = threadIdx.x >> 6;
    const int r     = blockIdx.x / BR;
    const int wslot = (blockIdx.x % BR) * 4 + wv;
    const int cnt   = min(cursor[r * CSTR], RCAP);
    if (cnt == 0) return;

    {
        const float4* __restrict__ W4 = reinterpret_cast<const float4*>(weight + (size_t)r * D * D);
        const float4* __restrict__ WS4 = reinterpret_cast<const float4*>(wself);
        for (int i = threadIdx.x; i < D * D / 4; i += 256) {
            const float4 w = W4[i];
            H4 o; o.v[0]=(_Float16)w.x; o.v[1]=(_Float16)w.y; o.v[2]=(_Float16)w.z; o.v[3]=(_Float16)w.w;
            *reinterpret_cast<H4*>(&lds_w[i * 4]) = o;
            const float4 u = WS4[i];
            H4 p; p.v[0]=(_Float16)u.x; p.v[1]=(_Float16)u.y; p.v[2]=(_Float16)u.z; p.v[3]=(_Float16)u.w;
            *reinterpret_cast<H4*>(&lds_ws[i * 4]) = p;
        }
    }
    __syncthreads();

    const int kbase = (lane >> 4) * 8;
    const int ncol  = lane & 15;

    f16x8 bw[4][2], bws[4][2];
    #pragma unroll
    for (int nt = 0; nt < 4; ++nt)
        #pragma unroll
        for (int ks = 0; ks < 2; ++ks) {
            f16x8 f, g;
            #pragma unroll
            for (int j = 0; j < 8; ++j) {
                f[j] = lds_w [(ks * 32 + kbase + j) * D + nt * 16 + ncol];
                g[j] = lds_ws[(ks * 32 + kbase + j) * D + nt * 16 + ncol];
            }
            bw[nt][ks] = f;
            bws[nt][ks] = g;
        }

    const unsigned* __restrict__ seg = rbucket + r * RCAP;

    for (int t = wslot; t * 16 < cnt; t += BR * 4) {
        const unsigned ent = seg[min(t * 16 + ncol, cnt - 1)];  // clamped tail: dup identical stores
        const int v = (int)(ent >> 16);
        const int s = (int)(ent & 0xFFFF);

        const float* __restrict__ hv = h + (size_t)v * D;
        const float* __restrict__ hs = h + (size_t)s * D;
        const f16x8 a0 = cvt_frag(hv + kbase);
        const f16x8 a1 = cvt_frag(hv + 32 + kbase);
        const f16x8 s0 = cvt_frag(hs + kbase);
        const f16x8 s1 = cvt_frag(hs + 32 + kbase);

        f32x4 c[4];
        #pragma unroll
        for (int nt = 0; nt < 4; ++nt) c[nt] = (f32x4){0.f, 0.f, 0.f, 0.f};

        #pragma unroll
        for (int nt = 0; nt < 4; ++nt) {
            c[nt] = __builtin_amdgcn_mfma_f32_16x16x32_f16(a0, bws[nt][0], c[nt], 0, 0, 0);
            c[nt] = __builtin_amdgcn_mfma_f32_16x16x32_f16(a1, bws[nt][1], c[nt], 0, 0, 0);
            c[nt] = __builtin_amdgcn_mfma_f32_16x16x32_f16(s0, bw[nt][0],  c[nt], 0, 0, 0);
            c[nt] = __builtin_amdgcn_mfma_f32_16x16x32_f16(s1, bw[nt][1],  c[nt], 0, 0, 0);
        }

        int vrow[4];
        #pragma unroll
        for (int q = 0; q < 4; ++q)
            vrow[q] = __shfl(v, (lane >> 4) * 4 + q, 64);
        #pragma unroll
        for (int nt = 0; nt < 4; ++nt)
            #pragma unroll
            for (int q = 0; q < 4; ++q)
                out[(size_t)vrow[q] * D + nt * 16 + ncol] = c[nt][q];
    }
}

extern "C" void kernel_launch(void* const* d_in, const int* in_sizes, int n_in,
                              void* d_out, int out_size, void* d_ws, size_t ws_size,
                              hipStream_t stream) {
    const float* h      = (const float*)d_in[0];
    const int*   edges  = (const int*)d_in[1];
    const float* weight = (const float*)d_in[2];
    const float* wself  = (const float*)d_in[3];
    float* out = (float*)d_out;

    char* ws = (char*)d_ws;
    u64*      packed  = (u64*)ws;
    int*      cursor  = (int*)(ws + WS_CURSOR);
    unsigned* rbucket = (unsigned*)(ws + WS_RBUCKET);

    k_zero<<<98, 256, 0, stream>>>(packed, cursor);
    k_scatdense<<<SC_BLK + DN_BLK, 256, 0, stream>>>(edges, h, wself, packed, out);
    k_fille<<<SC_BLK, 256, 0, stream>>>(edges, packed, cursor, rbucket);
    k_rel<<<NREL * BR, 256, 0, stream>>>(h, weight, wself, rbucket, cursor, out);
}